// Round 1
// baseline (30.279 us; speedup 1.0000x reference)
//
#include <hip/hip_runtime.h>

namespace {
constexpr int NPER = 512;   // blocks per segment
constexpr int UU   = 4;     // units per block
constexpr int KK   = 16;    // k
constexpr int NB   = 4096;  // total blocks
constexpr int STRIDE = 13;  // LDS row stride in floats (odd -> bank-conflict-light)
constexpr int NK = NB * KK; // 65536 output edges

__device__ __forceinline__ unsigned long long shfl_xor_u64(unsigned long long v, int mask) {
    unsigned int lo = (unsigned int)v;
    unsigned int hi = (unsigned int)(v >> 32);
    lo = (unsigned int)__shfl_xor((int)lo, mask, 64);
    hi = (unsigned int)__shfl_xor((int)hi, mask, 64);
    return ((unsigned long long)hi << 32) | lo;
}

__global__ __launch_bounds__(256) void knn_edge_kernel(const float* __restrict__ unit_pos,
                                                       int* __restrict__ out) {
    __shared__ float sp[NPER * STRIDE];
    const int wg  = blockIdx.x;        // 1024 workgroups, 4 rows each
    const int seg = (wg * 4) >> 9;     // / NPER
    const int tid = threadIdx.x;

    // Stage this segment's positions: 512 blocks x 12 floats (coalesced global reads).
    const float* gseg = unit_pos + (size_t)seg * NPER * UU * 3;
    for (int i = tid; i < NPER * UU * 3; i += 256) {
        int c = i / 12;
        int j = i - c * 12;
        sp[c * STRIDE + j] = gseg[i];
    }
    __syncthreads();

    const int wave = tid >> 6;
    const int lane = tid & 63;
    const int r_local  = (wg * 4 + wave) & (NPER - 1);
    const int r_global = seg * NPER + r_local;

    // Row block's 4 units + squared norms, replicating reference f32 arithmetic
    // (left-to-right adds, no FMA contraction).
    float xi[UU], yi[UU], zi[UU], ai[UU];
    #pragma unroll
    for (int u = 0; u < UU; ++u) {
        const float* p = &sp[r_local * STRIDE + u * 3];
        xi[u] = p[0]; yi[u] = p[1]; zi[u] = p[2];
        ai[u] = __fadd_rn(__fadd_rn(__fmul_rn(xi[u], xi[u]),
                                    __fmul_rn(yi[u], yi[u])),
                          __fmul_rn(zi[u], zi[u]));
    }

    // Each lane owns candidates c = lane + 64*t, t=0..7.
    unsigned long long key[8];
    #pragma unroll
    for (int t = 0; t < 8; ++t) {
        const int c = lane + 64 * t;
        const float* p = &sp[c * STRIDE];
        float xj[UU], yj[UU], zj[UU], aj[UU];
        #pragma unroll
        for (int v = 0; v < UU; ++v) {
            xj[v] = p[v * 3 + 0]; yj[v] = p[v * 3 + 1]; zj[v] = p[v * 3 + 2];
            aj[v] = __fadd_rn(__fadd_rn(__fmul_rn(xj[v], xj[v]),
                                        __fmul_rn(yj[v], yj[v])),
                              __fmul_rn(zj[v], zj[v]));
        }
        float m = __builtin_inff();
        #pragma unroll
        for (int u = 0; u < UU; ++u) {
            #pragma unroll
            for (int v = 0; v < UU; ++v) {
                float dot = __fadd_rn(__fadd_rn(__fmul_rn(xi[u], xj[v]),
                                                __fmul_rn(yi[u], yj[v])),
                                      __fmul_rn(zi[u], zj[v]));
                float d2 = __fsub_rn(__fadd_rn(ai[u], aj[v]), __fmul_rn(2.0f, dot));
                d2 = fmaxf(d2, 0.0f);
                m  = fminf(m, d2);
            }
        }
        // Reference compares f32 sqrt values; rounded sqrt collapses near-ties,
        // so apply the same sqrt (min/sqrt commute by weak monotonicity).
        float dist = __fsqrt_rn(m);
        key[t] = ((unsigned long long)__float_as_uint(dist) << 32) | (unsigned int)c;
    }

    // 16x: wave-wide min of (dist,col) keys; invalidate winner; lane it keeps col.
    int mycol = 0;
    #pragma unroll
    for (int it = 0; it < KK; ++it) {
        unsigned long long m = key[0];
        #pragma unroll
        for (int t = 1; t < 8; ++t) m = key[t] < m ? key[t] : m;
        #pragma unroll
        for (int off = 32; off >= 1; off >>= 1) {
            unsigned long long o = shfl_xor_u64(m, off);
            m = o < m ? o : m;
        }
        if (lane == it) mycol = (int)(m & 0xffffffffull);
        #pragma unroll
        for (int t = 0; t < 8; ++t)
            if (key[t] == m) key[t] = 0xffffffffffffffffull;
    }

    // Outputs concatenated flat: row_o[65536], col_o[65536], attr[65536] (int32).
    if (lane < KK) {
        const int o = r_global * KK + lane;
        out[o]          = r_global;
        out[NK + o]     = (seg * NPER) + mycol;
        out[2 * NK + o] = 0;
    }
}
} // namespace

extern "C" void kernel_launch(void* const* d_in, const int* in_sizes, int n_in,
                              void* d_out, int out_size, void* d_ws, size_t ws_size,
                              hipStream_t stream) {
    const float* unit_pos = (const float*)d_in[0];
    int* out = (int*)d_out;
    hipLaunchKernelGGL(knn_edge_kernel, dim3(NB / 4), dim3(256), 0, stream,
                       unit_pos, out);
}

// Round 2
// 25.385 us; speedup vs baseline: 1.1928x; 1.1928x over previous
//
#include <hip/hip_runtime.h>

namespace {
constexpr int NPER = 512;   // blocks per segment
constexpr int UU   = 4;     // units per block
constexpr int KK   = 16;    // k
constexpr int NB   = 4096;  // total blocks
constexpr int STRIDE = 13;  // LDS row stride in floats (odd -> conflict-light)
constexpr int NK = NB * KK; // 65536 output edges

// One 64-bit compare-exchange step of a wave min-reduction via DPP.
// CTRL/RM are compile-time (DPP control / row mask). Identity = all-ones
// (max u64 key), fed to shifted-in / masked-out lanes via `old`.
template <int CTRL, int RM>
__device__ __forceinline__ void dpp_min_step(unsigned& lo, unsigned& hi) {
    unsigned lo2 = (unsigned)__builtin_amdgcn_update_dpp(
        (int)0xFFFFFFFF, (int)lo, CTRL, RM, 0xF, false);
    unsigned hi2 = (unsigned)__builtin_amdgcn_update_dpp(
        (int)0xFFFFFFFF, (int)hi, CTRL, RM, 0xF, false);
    unsigned long long a = ((unsigned long long)hi << 32) | lo;
    unsigned long long b = ((unsigned long long)hi2 << 32) | lo2;
    if (b < a) { lo = lo2; hi = hi2; }
}

// Wave-wide u64 min -> SGPR pair (uniform return value).
// Standard gfx9 reduce: row_shr 1/2/4/8, row_bcast:15 (rows 1,3),
// row_bcast:31 (rows 2,3), result in lane 63, readlane.
__device__ __forceinline__ unsigned long long wave_min_u64(unsigned long long v) {
    unsigned lo = (unsigned)v, hi = (unsigned)(v >> 32);
    dpp_min_step<0x111, 0xF>(lo, hi);  // row_shr:1
    dpp_min_step<0x112, 0xF>(lo, hi);  // row_shr:2
    dpp_min_step<0x114, 0xF>(lo, hi);  // row_shr:4
    dpp_min_step<0x118, 0xF>(lo, hi);  // row_shr:8
    dpp_min_step<0x142, 0xA>(lo, hi);  // row_bcast:15 -> rows 1,3
    dpp_min_step<0x143, 0xC>(lo, hi);  // row_bcast:31 -> rows 2,3
    unsigned mlo = (unsigned)__builtin_amdgcn_readlane((int)lo, 63);
    unsigned mhi = (unsigned)__builtin_amdgcn_readlane((int)hi, 63);
    return ((unsigned long long)mhi << 32) | mlo;
}

__global__ __launch_bounds__(256) void knn_edge_kernel(const float* __restrict__ unit_pos,
                                                       int* __restrict__ out) {
    __shared__ float sp[NPER * STRIDE];
    const int wg  = blockIdx.x;        // 1024 workgroups, 4 rows each
    const int seg = (wg * 4) >> 9;     // / NPER
    const int tid = threadIdx.x;

    // Stage segment positions: 512 blocks x 12 floats, float4 global reads.
    const float4* g4 = reinterpret_cast<const float4*>(
        unit_pos + (size_t)seg * NPER * UU * 3);
    #pragma unroll
    for (int j = 0; j < 6; ++j) {
        const int i = tid + 256 * j;   // float4 index within segment (0..1535)
        const float4 v = g4[i];
        const int c = i / 3;           // candidate block
        const int part = (i - 3 * c) * 4;
        float* d = &sp[c * STRIDE + part];
        d[0] = v.x; d[1] = v.y; d[2] = v.z; d[3] = v.w;
    }
    __syncthreads();

    const int wave = tid >> 6;
    const int lane = tid & 63;
    const int r_local  = (wg * 4 + wave) & (NPER - 1);
    const int r_global = seg * NPER + r_local;

    // Row block's 4 units + squared norms, replicating reference f32 arithmetic
    // (left-to-right adds, no FMA contraction).
    float xi[UU], yi[UU], zi[UU], ai[UU];
    #pragma unroll
    for (int u = 0; u < UU; ++u) {
        const float* p = &sp[r_local * STRIDE + u * 3];
        xi[u] = p[0]; yi[u] = p[1]; zi[u] = p[2];
        ai[u] = __fadd_rn(__fadd_rn(__fmul_rn(xi[u], xi[u]),
                                    __fmul_rn(yi[u], yi[u])),
                          __fmul_rn(zi[u], zi[u]));
    }

    // Each lane owns candidates c = lane + 64*t, t=0..7.
    unsigned long long key[8];
    #pragma unroll
    for (int t = 0; t < 8; ++t) {
        const int c = lane + 64 * t;
        const float* p = &sp[c * STRIDE];
        float xj[UU], yj[UU], zj[UU], aj[UU];
        #pragma unroll
        for (int v = 0; v < UU; ++v) {
            xj[v] = p[v * 3 + 0]; yj[v] = p[v * 3 + 1]; zj[v] = p[v * 3 + 2];
            aj[v] = __fadd_rn(__fadd_rn(__fmul_rn(xj[v], xj[v]),
                                        __fmul_rn(yj[v], yj[v])),
                              __fmul_rn(zj[v], zj[v]));
        }
        float m = __builtin_inff();
        #pragma unroll
        for (int u = 0; u < UU; ++u) {
            #pragma unroll
            for (int v = 0; v < UU; ++v) {
                float dot = __fadd_rn(__fadd_rn(__fmul_rn(xi[u], xj[v]),
                                                __fmul_rn(yi[u], yj[v])),
                                      __fmul_rn(zi[u], zj[v]));
                float d2 = __fsub_rn(__fadd_rn(ai[u], aj[v]), __fmul_rn(2.0f, dot));
                d2 = fmaxf(d2, 0.0f);
                m  = fminf(m, d2);
            }
        }
        // Reference compares f32 sqrt values; rounded sqrt collapses near-ties
        // into col-tie-broken equalities, so apply the same sqrt (min/sqrt
        // commute by weak monotonicity).
        float dist = __fsqrt_rn(m);
        key[t] = ((unsigned long long)__float_as_uint(dist) << 32) | (unsigned int)c;
    }

    // 16x: wave-wide min of (dist,col) keys via DPP; invalidate winner via
    // SGPR-pair broadcast compare; lane `it` keeps winner col.
    int mycol = 0;
    #pragma unroll
    for (int it = 0; it < KK; ++it) {
        unsigned long long lm = key[0];
        #pragma unroll
        for (int t = 1; t < 8; ++t) lm = key[t] < lm ? key[t] : lm;
        const unsigned long long m = wave_min_u64(lm);  // uniform (SGPR pair)
        if (lane == it) mycol = (int)(unsigned)(m & 0xffffffffull);
        #pragma unroll
        for (int t = 0; t < 8; ++t)
            if (key[t] == m) key[t] = 0xffffffffffffffffull;
    }

    // Outputs concatenated flat: row_o[65536], col_o[65536], attr[65536] (int32).
    if (lane < KK) {
        const int o = r_global * KK + lane;
        out[o]          = r_global;
        out[NK + o]     = (seg * NPER) + mycol;
        out[2 * NK + o] = 0;
    }
}
} // namespace

extern "C" void kernel_launch(void* const* d_in, const int* in_sizes, int n_in,
                              void* d_out, int out_size, void* d_ws, size_t ws_size,
                              hipStream_t stream) {
    const float* unit_pos = (const float*)d_in[0];
    int* out = (int*)d_out;
    hipLaunchKernelGGL(knn_edge_kernel, dim3(NB / 4), dim3(256), 0, stream,
                       unit_pos, out);
}